// Round 9
// baseline (271.959 us; speedup 1.0000x reference)
//
#include <hip/hip_runtime.h>
#include <hip/hip_bf16.h>
#include <math.h>

// Problem constants
#define D_MODEL 2048
#define N_H     16
#define D_H     128
#define D_CQ    768
#define D_CKV   512
#define D_HR    64
#define SEQ     2048
#define N_ACT1  1408  // 768 (cq) + 512 (ckv) + 64 (kr) + 64 pad (junk)
#define NSPLIT  2
#define ATT_SCALE 0.07216878364870323f  // 1/sqrt(192), pre-applied to Q

typedef short bf16x8 __attribute__((ext_vector_type(8)));
typedef short short4v __attribute__((ext_vector_type(4)));
typedef float f32x4  __attribute__((ext_vector_type(4)));

__device__ inline short f2bf(float f) {
  union { float f; unsigned u; } v; v.f = f;
  unsigned r = (v.u + 0x7fff + ((v.u >> 16) & 1)) >> 16;
  return (short)r;
}
__device__ inline float bf2f(short s) {
  union { float f; unsigned u; } v; v.u = ((unsigned)(unsigned short)s) << 16;
  return v.f;
}

// async global->LDS, 16B per lane; lds dest must be wave-uniform base
__device__ inline void gld_lds16(const void* g, void* l) {
#if __has_builtin(__builtin_amdgcn_global_load_lds)
  __builtin_amdgcn_global_load_lds(
      (const __attribute__((address_space(1))) unsigned int*)g,
      (__attribute__((address_space(3))) unsigned int*)l, 16, 0, 0);
#else
  int lane = threadIdx.x & 63;
  *((uint4*)l + lane) = *(const uint4*)g;
#endif
}

// ---------------------------------------------------------------------------
// Fused weight cast+transpose (8 jobs) + RMSNorm, one launch.
// ---------------------------------------------------------------------------
struct CastJobs {
  const float* src[8];
  short* dst[8];
  int K[8];
  int pref[9];
  int nx[8];
};

__global__ __launch_bounds__(256) void prep_all(
    CastJobs J, const float* __restrict__ x, const float* __restrict__ wn,
    short* __restrict__ hb) {
  int bid = blockIdx.x;
  int tid = threadIdx.x;

  if (bid >= J.pref[8]) {
    // ---- RMSNorm row ----
    int row = bid - J.pref[8];
    const float* xr = x + (size_t)row * D_MODEL;
    float ss = 0.f;
    for (int i = tid; i < D_MODEL; i += 256) { float v = xr[i]; ss += v * v; }
    __shared__ float red[256];
    red[tid] = ss;
    __syncthreads();
    for (int s = 128; s > 0; s >>= 1) {
      if (tid < s) red[tid] += red[tid + s];
      __syncthreads();
    }
    float scale = rsqrtf(red[0] / (float)D_MODEL + 1.1920929e-7f);
    short* hbr = hb + (size_t)row * D_MODEL;
    for (int i = tid; i < D_MODEL; i += 256) hbr[i] = f2bf(xr[i] * scale * wn[i]);
    return;
  }

  // ---- weight cast+transpose ----
  int j = 0;
#pragma unroll
  for (int t = 0; t < 8; t++)
    if (bid >= J.pref[t + 1]) j = t + 1;
  int lid = bid - J.pref[j];
  int nx = J.nx[j];
  int ty = lid / nx, tx = lid - ty * nx;
  int n0 = tx * 64, k0 = ty * 64;
  int K = J.K[j];
  const float* W = J.src[j];
  short* Wt = J.dst[j];
  int Nfull = nx * 64;

  __shared__ short T[64][68];
#pragma unroll
  for (int it = 0; it < 16; it++) {
    int idx = it * 256 + tid;
    int r = idx >> 6, c = idx & 63;
    T[c][r] = f2bf(W[(size_t)(k0 + r) * Nfull + n0 + c]);
  }
  __syncthreads();
#pragma unroll
  for (int it = 0; it < 16; it++) {
    int idx = it * 256 + tid;
    int r = idx >> 6, c = idx & 63;
    Wt[(size_t)(n0 + r) * K + k0 + c] = T[r][c];
  }
}

// ---------------------------------------------------------------------------
// BM=64 x BN=128 MFMA bf16 GEMM body (4 waves of 32x64) — modes 3/4 (qkv).
// mode 3: q-pack (PRE-SCALED by 1/sqrt(192)) + fused RoPE (cols>=2048);
// mode 4: k-pack + DIRECT vt transpose write (cols>=2048).
// Both-sides XOR swizzle on As/Bs; dbuf early-issue staging.
// ---------------------------------------------------------------------------
__device__ __forceinline__ void gemm64_body(
    const short* __restrict__ A, const short* __restrict__ Bt,
    short* __restrict__ Cb, short* __restrict__ Cb2,
    int M, int N, int K, int lda, int ldb,
    int mode, int bxx, int byy) {
  __shared__ short As[2 * 64 * 64];
  __shared__ short Bs[2 * 128 * 64];
  int tid = threadIdx.x;
  int w = tid >> 6, l = tid & 63;
  int lq = l >> 4, l16 = l & 15;
  int bm = byy * 64, bn = bxx * 128;
  int wr = w >> 1, wc = w & 1;
  int wm0 = wr * 32, wn0 = wc * 64;

  f32x4 acc[2][4];
#pragma unroll
  for (int i = 0; i < 2; i++)
#pragma unroll
    for (int j = 0; j < 4; j++) acc[i][j] = (f32x4)0.f;

  int rsub = (l >> 3);                     // row-within-8 (r0 is mult of 8)
  int csub = ((l & 7) ^ rsub) << 3;        // pre-swizzled source chunk

  auto stage = [&](int buf, int k0) {
    short* Asb = As + buf * (64 * 64);
    short* Bsb = Bs + buf * (128 * 64);
#pragma unroll
    for (int i = 0; i < 2; i++) {
      int r0 = i * 32 + w * 8;
      gld_lds16(A + (size_t)(bm + r0 + rsub) * lda + k0 + csub, Asb + r0 * 64);
    }
#pragma unroll
    for (int i = 0; i < 4; i++) {
      int r0 = i * 32 + w * 8;
      gld_lds16(Bt + (size_t)(bn + r0 + rsub) * ldb + k0 + csub, Bsb + r0 * 64);
    }
  };

  stage(0, 0);
  int cur = 0;
  for (int k0 = 0; k0 < K; k0 += 64) {
    __syncthreads();
    if (k0 + 64 < K) stage(cur ^ 1, k0 + 64);
    const short* Asb = As + cur * (64 * 64);
    const short* Bsb = Bs + cur * (128 * 64);

#pragma unroll
    for (int ks = 0; ks < 2; ks++) {
      bf16x8 af[2], bfr[4];
      int sw = ((ks * 4 + lq) ^ (l16 & 7)) << 3;
#pragma unroll
      for (int mt = 0; mt < 2; mt++)
        af[mt] = *(const bf16x8*)&Asb[(wm0 + mt * 16 + l16) * 64 + sw];
#pragma unroll
      for (int nt = 0; nt < 4; nt++)
        bfr[nt] = *(const bf16x8*)&Bsb[(wn0 + nt * 16 + l16) * 64 + sw];
#pragma unroll
      for (int mt = 0; mt < 2; mt++)
#pragma unroll
        for (int nt = 0; nt < 4; nt++)
          acc[mt][nt] = __builtin_amdgcn_mfma_f32_16x16x32_bf16(af[mt], bfr[nt], acc[mt][nt], 0, 0, 0);
    }
    cur ^= 1;
  }

#pragma unroll
  for (int mt = 0; mt < 2; mt++)
#pragma unroll
    for (int nt = 0; nt < 4; nt++) {
      int col = bn + wn0 + nt * 16 + l16;
      int row0 = bm + wm0 + mt * 16 + lq * 4;
      if (mode == 4 && col >= 2048) {
        // direct vt transpose: vt[(col-2048)*SEQ + row0..row0+3]
        int cc = col - 2048;
        short4v v4;
#pragma unroll
        for (int i = 0; i < 4; i++) v4[i] = f2bf(acc[mt][nt][i]);
        *(short4v*)&Cb2[(size_t)cc * SEQ + row0] = v4;
        continue;
      }
#pragma unroll
      for (int i = 0; i < 4; i++) {
        int row = row0 + i;
        float v = acc[mt][nt][i];
        if (mode == 3) {
          if (col < 2048) {
            Cb[((size_t)(col >> 7) * M + row) * 192 + (col & 127)] =
                f2bf(v * ATT_SCALE);
          } else {
            int cc = col - 2048;
            int hh = cc >> 6, dd = cc & 63;
            float partner = __shfl_xor(v, 1);
            float inv = __expf(-((float)(dd & ~1) / 64.0f) * 9.210340372f); // ln 10000
            float ang = (float)row * inv;
            float c = __cosf(ang), s = __sinf(ang);
            float res = ((dd & 1) == 0) ? (v * c - partner * s)
                                        : (partner * s + v * c);
            Cb[((size_t)hh * M + row) * 192 + 128 + dd] = f2bf(res * ATT_SCALE);
          }
        } else {  // mode 4, col < 2048: k-pack
          Cb[((size_t)(col >> 7) * M + row) * 192 + (col & 127)] = f2bf(v);
        }
      }
    }
}

// Fused GEMM2+GEMM3 (both consume act1): bx<24 -> qb (N=3072, K=768, mode 3);
// else -> kb/vt (N=4096, K=512, mode 4). One full-device launch (1792 blocks).
__global__ __launch_bounds__(256) void gemm_qkv(
    const short* __restrict__ act1, const short* __restrict__ WT2,
    const short* __restrict__ WT3, short* __restrict__ qb,
    short* __restrict__ kb, short* __restrict__ vt) {
  int bx = blockIdx.x;
  if (bx < 24) {
    gemm64_body(act1, WT2, qb, nullptr,
                SEQ, 3072, D_CQ, N_ACT1, D_CQ, 3, bx, blockIdx.y);
  } else {
    gemm64_body(act1 + 768, WT3, kb, vt,
                SEQ, 4096, D_CKV, N_ACT1, D_CKV, 4, bx - 24, blockIdx.y);
  }
}

// ---------------------------------------------------------------------------
// 64x64 MFMA bf16 GEMM (4 waves of 32x32) — modes 0 (f32 out + addv) and
// 1 (bf16 row-major). r8-verified: higher block count for latency-bound
// small-N shapes (final GEMM 1024 blocks = 4/CU). LDS 32KB/block.
// ---------------------------------------------------------------------------
__global__ __launch_bounds__(256, 4) void gemm_bf16_6464(
    const short* __restrict__ A, const short* __restrict__ Bt,
    float* __restrict__ Cf, short* __restrict__ Cb,
    const float* __restrict__ addv, int M, int N, int K, int lda, int ldb,
    int mode) {
  __shared__ short As[2 * 64 * 64];
  __shared__ short Bs[2 * 64 * 64];
  int tid = threadIdx.x;
  int w = tid >> 6, l = tid & 63;
  int lq = l >> 4, l16 = l & 15;
  int bm = blockIdx.y * 64, bn = blockIdx.x * 64;
  int wr = w >> 1, wc = w & 1;
  int wm0 = wr * 32, wn0 = wc * 32;

  f32x4 acc[2][2];
#pragma unroll
  for (int i = 0; i < 2; i++)
#pragma unroll
    for (int j = 0; j < 2; j++) acc[i][j] = (f32x4)0.f;

  int rsub = (l >> 3);
  int csub = ((l & 7) ^ rsub) << 3;

  auto stage = [&](int buf, int k0) {
    short* Asb = As + buf * (64 * 64);
    short* Bsb = Bs + buf * (64 * 64);
#pragma unroll
    for (int i = 0; i < 2; i++) {
      int r0 = i * 32 + w * 8;
      gld_lds16(A + (size_t)(bm + r0 + rsub) * lda + k0 + csub, Asb + r0 * 64);
      gld_lds16(Bt + (size_t)(bn + r0 + rsub) * ldb + k0 + csub, Bsb + r0 * 64);
    }
  };

  stage(0, 0);
  int cur = 0;
  for (int k0 = 0; k0 < K; k0 += 64) {
    __syncthreads();
    if (k0 + 64 < K) stage(cur ^ 1, k0 + 64);
    const short* Asb = As + cur * (64 * 64);
    const short* Bsb = Bs + cur * (64 * 64);

#pragma unroll
    for (int ks = 0; ks < 2; ks++) {
      bf16x8 af[2], bfr[2];
      int sw = ((ks * 4 + lq) ^ (l16 & 7)) << 3;
#pragma unroll
      for (int mt = 0; mt < 2; mt++)
        af[mt] = *(const bf16x8*)&Asb[(wm0 + mt * 16 + l16) * 64 + sw];
#pragma unroll
      for (int nt = 0; nt < 2; nt++)
        bfr[nt] = *(const bf16x8*)&Bsb[(wn0 + nt * 16 + l16) * 64 + sw];
#pragma unroll
      for (int mt = 0; mt < 2; mt++)
#pragma unroll
        for (int nt = 0; nt < 2; nt++)
          acc[mt][nt] = __builtin_amdgcn_mfma_f32_16x16x32_bf16(af[mt], bfr[nt], acc[mt][nt], 0, 0, 0);
    }
    cur ^= 1;
  }

#pragma unroll
  for (int mt = 0; mt < 2; mt++)
#pragma unroll
    for (int nt = 0; nt < 2; nt++) {
      int col = bn + wn0 + nt * 16 + l16;
      int row0 = bm + wm0 + mt * 16 + lq * 4;
#pragma unroll
      for (int i = 0; i < 4; i++) {
        int row = row0 + i;
        float v = acc[mt][nt][i];
        if (mode == 0) {
          size_t off = (size_t)row * N + col;
          if (addv) v += addv[off];
          Cf[off] = v;
        } else {  // mode 1
          Cb[(size_t)row * N + col] = f2bf(v);
        }
      }
    }
}

// ---------------------------------------------------------------------------
// RoPE k: read bf16 cols 1280..1343 of act1, rotate, broadcast to kb heads.
// ---------------------------------------------------------------------------
__global__ void rope_k_kernel(const short* __restrict__ act1, short* __restrict__ kb) {
  int idx = blockIdx.x * blockDim.x + threadIdx.x;
  if (idx >= SEQ * 32) return;
  int j = idx & 31;
  int s = idx >> 5;
  const short* p = act1 + (size_t)s * N_ACT1 + 1280 + 2 * j;
  float x0 = bf2f(p[0]), x1 = bf2f(p[1]);
  float inv = __expf(-((float)(2 * j) / 64.0f) * 9.210340372f);
  float ang = (float)s * inv;
  float c = __cosf(ang), sn = __sinf(ang);
  short b0 = f2bf(x0 * c - x1 * sn);
  short b1 = f2bf(x0 * sn + x1 * c);
#pragma unroll
  for (int hh = 0; hh < N_H; hh++) {
    short* k = kb + ((size_t)hh * SEQ + s) * 192 + 128 + 2 * j;
    k[0] = b0;
    k[1] = b1;
  }
}

// ---------------------------------------------------------------------------
// MFMA bf16 flash attention, NSPLIT=2 split-K, NO-MAX softmax, XCD-aware.
// Round-9: NSPLIT 4->2 (halves Opart write + merge read traffic) with
// CONSTANT-SUM PAIRING: qt = split ? r2 : 15-r2, so any two consecutive
// blocks sum to 17 tile-iters -> per-CU balance robust to scheduler mapping.
// Q arrives PRE-SCALED by 1/sqrt(192) (folded into gemm_qkv mode 3) -> exp
// needs no multiply. r7 structure otherwise: TQ=128, Ks dbuf + loop-top
// prefetch, V staged at loop top, both-sides swizzle, setprio on MFMA.
// ---------------------------------------------------------------------------
#define TQ 128
#define TK 64
#define KSZ (TK * 192)

__global__ __launch_bounds__(256, 2) void attn_mfma(
    const short* __restrict__ qb, const short* __restrict__ kb,
    const short* __restrict__ vt, short* __restrict__ Opart,
    float* __restrict__ Lpart) {
  int bid = blockIdx.x;
  int h = bid & 15;
  int rest = bid >> 4;            // [0, 32)
  int r2 = rest >> 1;             // [0, 16)
  int split = rest & 1;
  int qt = split ? r2 : 15 - r2;  // pair-sum = const 17 iters
  int q0 = qt * TQ;
  int nk = 2 * (qt + 1);          // 64-key tiles covering rows q0..q0+127
  int tid = threadIdx.x;
  int wave = tid >> 6, lane = tid & 63;
  int lq = lane >> 4, l16 = lane & 15;

  __shared__ short Ks[2 * KSZ];    // dbuf [64 keys][24 x 16B], chunk^=(row&7)
  __shared__ short Vs[128 * 64];   // [128 dims][8 x 16B chunks], chunk^=(dim&7)
  __shared__ short Ps[TQ * 64];    // [128 rows][8 x 16B chunks], chunk^=(row&7)

  // ---- Q fragments: wave owns rows q0 + wave*32 .. +31 (2 row-tiles) ----
  bf16x8 qf[2][6];
  {
    const short* qp = qb + ((size_t)h * SEQ + q0 + wave * 32 + l16) * 192;
#pragma unroll
    for (int mt = 0; mt < 2; mt++)
#pragma unroll
      for (int ks = 0; ks < 6; ks++)
        qf[mt][ks] = *(const bf16x8*)(qp + (size_t)mt * 16 * 192 + ks * 32 + lq * 8);
  }

  bf16x8 ones;
#pragma unroll
  for (int i = 0; i < 8; i++) ones[i] = (short)0x3F80;  // bf16 1.0

  f32x4 O[2][8];
  f32x4 Ol[2];
#pragma unroll
  for (int mt = 0; mt < 2; mt++) {
    Ol[mt] = (f32x4)0.f;
#pragma unroll
    for (int i = 0; i < 8; i++) O[mt][i] = (f32x4)0.f;
  }

  // ---- K staging plan: 1536 16B slots (64 rows x 24 chunks), 6/thread.
  int goffK[6];
#pragma unroll
  for (int i = 0; i < 6; i++) {
    int s = i * 256 + tid;
    int r = s / 24;
    int c = s - r * 24;
    goffK[i] = r * 192 + ((c ^ (r & 7)) << 3);
  }
  // ---- V staging plan: 1024 16B slots (128 dims x 8 chunks), 4/thread.
  int goffV[4];
  int vrow[4];
#pragma unroll
  for (int i = 0; i < 4; i++) {
    int s = i * 256 + tid;
    int d = s >> 3;
    int p = s & 7;
    vrow[i] = d;
    goffV[i] = (p ^ (d & 7)) << 3;
  }
  const short* kb_h = kb + (size_t)h * SEQ * 192;
  const short* vt_h = vt + (size_t)h * 128 * SEQ;

  auto stage_k = [&](int k0s, int buf) {
#pragma unroll
    for (int i = 0; i < 6; i++)
      gld_lds16(kb_h + (size_t)k0s * 192 + goffK[i],
                Ks + buf * KSZ + (size_t)(i * 256 + wave * 64) * 8);
  };
  auto stage_v = [&](int k0s) {
#pragma unroll
    for (int i = 0; i < 4; i++)
      gld_lds16(vt_h + (size_t)vrow[i] * SEQ + k0s + goffV[i],
                Vs + (size_t)(i * 256 + wave * 64) * 8);
  };

  if (split < nk) stage_k(split * TK, 0);
  int kbuf = 0;

  for (int t = split; t < nk; t += NSPLIT) {
    int k0 = t * TK;
    __syncthreads();  // drains vmcnt: Ks[kbuf](t) visible; PV(t-1) reads done

    stage_v(k0);      // covered by QK^T+exp below
    if (t + NSPLIT < nk) stage_k((t + NSPLIT) * TK, kbuf ^ 1);  // dbuf prefetch

    // ---- S = Q K^T (swizzled Ks reads; B-frag shared across row-tiles) ----
    const short* Ksb = Ks + kbuf * KSZ;
    f32x4 S[2][4];
#pragma unroll
    for (int mt = 0; mt < 2; mt++)
#pragma unroll
      for (int nt = 0; nt < 4; nt++) S[mt][nt] = (f32x4)0.f;
    __builtin_amdgcn_s_setprio(1);
#pragma unroll
    for (int ks = 0; ks < 6; ks++) {
#pragma unroll
      for (int nt = 0; nt < 4; nt++) {
        int row = nt * 16 + l16;
        bf16x8 b = *(const bf16x8*)&Ksb[row * 192 +
                                        (((ks * 4 + lq) ^ (l16 & 7)) << 3)];
#pragma unroll
        for (int mt = 0; mt < 2; mt++)
          S[mt][nt] = __builtin_amdgcn_mfma_f32_16x16x32_bf16(qf[mt][ks], b, S[mt][nt], 0, 0, 0);
      }
    }
    __builtin_amdgcn_s_setprio(0);

    // ---- P = exp(S), masked -> 0 (Q pre-scaled); swizzled Ps writes ----
#pragma unroll
    for (int mt = 0; mt < 2; mt++)
#pragma unroll
      for (int i = 0; i < 4; i++) {
        int pr = wave * 32 + mt * 16 + lq * 4 + i;
        int row = q0 + pr;
        bool may = (k0 + 63 > row);
#pragma unroll
        for (int nt = 0; nt < 4; nt++) {
          float p;
          if (may && (k0 + nt * 16 + l16 > row)) p = 0.f;
          else p = __expf(S[mt][nt][i]);
          int j = nt * 16 + l16;
          Ps[pr * 64 + ((((j >> 3) ^ (pr & 7)) << 3) | (j & 7))] = f2bf(p);
        }
      }

    __syncthreads();  // drains vmcnt: Vs(t) + Ks prefetch visible

    // ---- O += P V ; Ol += P @ ones (Vs B-frag shared across row-tiles) ----
    __builtin_amdgcn_s_setprio(1);
#pragma unroll
    for (int kh = 0; kh < 2; kh++) {
      bf16x8 a[2];
#pragma unroll
      for (int mt = 0; mt < 2; mt++) {
        int prw = wave * 32 + mt * 16 + l16;
        a[mt] = *(const bf16x8*)&Ps[prw * 64 +
                                    (((kh * 4 + lq) ^ (l16 & 7)) << 3)];
        Ol[mt] = __builtin_amdgcn_mfma_f32_16x16x32_bf16(a[mt], ones, Ol[mt], 0, 0, 0);
      }
#pragma unroll
      for (int nt = 0; nt < 8; nt++) {
        int d = nt * 16 + l16;
        bf16x8 b = *(const bf16x8*)&Vs[d * 64 +
                                       (((kh * 4 + lq) ^ (d & 7)) << 3)];
#pragma unroll
        for (int mt = 0; mt < 2; mt++)
          O[mt][nt] = __builtin_amdgcn_mfma_f32_16x16x32_bf16(a[mt], b, O[mt][nt], 0, 0, 0);
      }
    }
    __builtin_amdgcn_s_setprio(0);
    kbuf ^= 1;
  }

  // ---- partial epilogue ----
#pragma unroll
  for (int mt = 0; mt < 2; mt++)
#pragma unroll
    for (int i = 0; i < 4; i++) {
      int row = q0 + wave * 32 + mt * 16 + lq * 4 + i;
      size_t base = ((size_t)(split * N_H + h) * SEQ + row);
      size_t obase = base * 128;
#pragma unroll
      for (int nt = 0; nt < 8; nt++)
        Opart[obase + nt * 16 + l16] = f2bf(O[mt][nt][i]);
      if (l16 == 0) Lpart[base] = Ol[mt][i];
    }
}

// ---------------------------------------------------------------------------
// merge the NSPLIT split-K partials -> ao bf16 (s, h*128+d).
// ---------------------------------------------------------------------------
__global__ __launch_bounds__(256) void attn_merge(
    const short* __restrict__ Opart, const float* __restrict__ Lpart,
    short* __restrict__ aob) {
  int q0 = blockIdx.x * 16;
  int h = blockIdx.y;
  int tid = threadIdx.x;
#pragma unroll
  for (int i = 0; i < 8; i++) {
    int c = i * 256 + tid;
    int row = q0 + (c >> 7), d = c & 127;
    float denom = 0.f, num = 0.f;
#pragma unroll
    for (int p = 0; p < NSPLIT; p++) {
      size_t base = (size_t)(p * N_H + h) * SEQ + row;
      denom += Lpart[base];
      num += bf2f(Opart[base * 128 + d]);
    }
    aob[(size_t)row * D_MODEL + h * 128 + d] = f2bf(num / denom);
  }
}

// ---------------------------------------------------------------------------
extern "C" void kernel_launch(void* const* d_in, const int* in_sizes, int n_in,
                              void* d_out, int out_size, void* d_ws, size_t ws_size,
                              hipStream_t stream) {
  const float* x      = (const float*)d_in[0];
  // d_in[1] = mask: causal triu, handled structurally — not read.
  const float* w_norm = (const float*)d_in[2];
  const float* w_cq   = (const float*)d_in[3];
  const float* w_q    = (const float*)d_in[4];
  const float* w_qr   = (const float*)d_in[5];
  const float* w_ckv  = (const float*)d_in[6];
  const float* w_k    = (const float*)d_in[7];
  const float* w_kr   = (const float*)d_in[8];
  const float* w_v    = (const float*)d_in[9];
  const float* w_o    = (const float*)d_in[10];
  float* out = (float*)d_out;

  char* ws = (char*)d_ws;
  short* h_bf  = (short*)ws;  ws += (size_t)SEQ * D_MODEL * 2;
  short* act1  = (short*)ws;  ws += (size_t)SEQ * N_ACT1 * 2;   // [s][1408]: cq|ckv|kr|junk
  short* qb    = (short*)ws;  ws += (size_t)N_H * SEQ * 192 * 2;
  short* kb    = (short*)ws;  ws += (size_t)N_H * SEQ * 192 * 2;
  short* vt    = (short*)ws;  ws += (size_t)SEQ * D_MODEL * 2;
  short* ao_bf = (short*)ws;  ws += (size_t)SEQ * D_MODEL * 2;
  short* Opart = (short*)ws;  ws += (size_t)NSPLIT * N_H * SEQ * 128 * 2;
  float* Lpart = (float*)ws;  ws += (size_t)NSPLIT * N_H * SEQ * 4;
  short* WT1   = (short*)ws;  ws += (size_t)N_ACT1 * D_MODEL * 2;   // [1408][2048]
  short* WT2   = (short*)ws;  ws += (size_t)3072 * D_CQ * 2;        // [3072][768]
  short* WT3   = (short*)ws;  ws += (size_t)4096 * D_CKV * 2;       // [4096][512]
  short* WTO   = (short*)ws;  ws += (size_t)D_MODEL * D_MODEL * 2;  // [2048][2048]

  // ---- fused weight casts + rmsnorm (1 launch) ----
  CastJobs J;
  J.src[0] = w_cq;  J.dst[0] = WT1;                              J.K[0] = D_MODEL; J.nx[0] = D_CQ / 64;
  J.src[1] = w_ckv; J.dst[1] = WT1 + (size_t)768 * D_MODEL;      J.K[1] = D_MODEL; J.nx[1] = D_CKV / 64;
  J.src[2] = w_kr;  J.dst[2] = WT1 + (size_t)1280 * D_MODEL;     J.K[2] = D_MODEL; J.nx[2] = D_HR / 64;
  J.src[3] = w_q;   J.dst[3] = WT2;                              J.K[3] = D_CQ;    J.nx[3] = 2048 / 64;
  J.src[4] = w_qr;  J.dst[4] = WT2 + (size_t)2048 * D_CQ;        J.K[4] = D_CQ;    J.nx[4] = 1024 / 64;
  J.src[5] = w_k;   J.dst[5] = WT3;                              J.K[5] = D_CKV;   J.nx[5] = 2048 / 64;
  J.src[6] = w_v;   J.dst[6] = WT3 + (size_t)2048 * D_CKV;       J.K[6] = D_CKV;   J.nx[6] = 2048 / 64;
  J.src[7] = w_o;   J.dst[7] = WTO;                              J.K[7] = D_MODEL; J.nx[7] = 2048 / 64;
  int pref = 0;
  for (int j = 0; j < 8; j++) {
    J.pref[j] = pref;
    pref += J.nx[j] * (J.K[j] / 64);
  }
  J.pref[8] = pref;
  prep_all<<<pref + SEQ, 256, 0, stream>>>(J, x, w_norm, h_bf);

  // GEMM1: act1 = h @ [w_cq | w_ckv | w_kr | junk]  (64x64 tile: 704 blocks)
  gemm_bf16_6464<<<dim3(N_ACT1 / 64, SEQ / 64), 256, 0, stream>>>(
      h_bf, WT1, nullptr, act1, nullptr, SEQ, N_ACT1, D_MODEL,
      D_MODEL, D_MODEL, 1);

  rope_k_kernel<<<(SEQ * 32 + 255) / 256, 256, 0, stream>>>(act1, kb);

  // GEMM2+3 fused: qb (rope, pre-scaled) | kb | vt (direct transpose)
  gemm_qkv<<<dim3(24 + 32, SEQ / 64), 256, 0, stream>>>(
      act1, WT2, WT3, qb, kb, vt);

  attn_mfma<<<dim3((SEQ / TQ) * NSPLIT * N_H), 256, 0, stream>>>(qb, kb, vt, Opart, Lpart);
  attn_merge<<<dim3(SEQ / 16, N_H), 256, 0, stream>>>(Opart, Lpart, ao_bf);

  // out = ao @ w_o + x   (64x64 tile: 1024 blocks = 4/CU)
  gemm_bf16_6464<<<dim3(D_MODEL / 64, SEQ / 64), 256, 0, stream>>>(
      ao_bf, WTO, out, nullptr, x, SEQ, D_MODEL, D_MODEL,
      D_MODEL, D_MODEL, 0);
}

// Round 10
// 261.870 us; speedup vs baseline: 1.0385x; 1.0385x over previous
//
#include <hip/hip_runtime.h>
#include <hip/hip_bf16.h>
#include <math.h>

// Problem constants
#define D_MODEL 2048
#define N_H     16
#define D_H     128
#define D_CQ    768
#define D_CKV   512
#define D_HR    64
#define SEQ     2048
#define N_ACT1  1408  // 768 (cq) + 512 (ckv) + 64 (kr) + 64 pad (junk)
#define NSPLIT  4
#define ATT_SCALE 0.07216878364870323f  // 1/sqrt(192), pre-applied to Q

typedef short bf16x8 __attribute__((ext_vector_type(8)));
typedef short short4v __attribute__((ext_vector_type(4)));
typedef float f32x4  __attribute__((ext_vector_type(4)));

__device__ inline short f2bf(float f) {
  union { float f; unsigned u; } v; v.f = f;
  unsigned r = (v.u + 0x7fff + ((v.u >> 16) & 1)) >> 16;
  return (short)r;
}
__device__ inline float bf2f(short s) {
  union { float f; unsigned u; } v; v.u = ((unsigned)(unsigned short)s) << 16;
  return v.f;
}

// async global->LDS, 16B per lane; lds dest must be wave-uniform base
__device__ inline void gld_lds16(const void* g, void* l) {
#if __has_builtin(__builtin_amdgcn_global_load_lds)
  __builtin_amdgcn_global_load_lds(
      (const __attribute__((address_space(1))) unsigned int*)g,
      (__attribute__((address_space(3))) unsigned int*)l, 16, 0, 0);
#else
  int lane = threadIdx.x & 63;
  *((uint4*)l + lane) = *(const uint4*)g;
#endif
}

// ---------------------------------------------------------------------------
// Fused weight cast+transpose (8 jobs) + RMSNorm, one launch.
// ---------------------------------------------------------------------------
struct CastJobs {
  const float* src[8];
  short* dst[8];
  int K[8];
  int pref[9];
  int nx[8];
};

__global__ __launch_bounds__(256) void prep_all(
    CastJobs J, const float* __restrict__ x, const float* __restrict__ wn,
    short* __restrict__ hb) {
  int bid = blockIdx.x;
  int tid = threadIdx.x;

  if (bid >= J.pref[8]) {
    // ---- RMSNorm row ----
    int row = bid - J.pref[8];
    const float* xr = x + (size_t)row * D_MODEL;
    float ss = 0.f;
    for (int i = tid; i < D_MODEL; i += 256) { float v = xr[i]; ss += v * v; }
    __shared__ float red[256];
    red[tid] = ss;
    __syncthreads();
    for (int s = 128; s > 0; s >>= 1) {
      if (tid < s) red[tid] += red[tid + s];
      __syncthreads();
    }
    float scale = rsqrtf(red[0] / (float)D_MODEL + 1.1920929e-7f);
    short* hbr = hb + (size_t)row * D_MODEL;
    for (int i = tid; i < D_MODEL; i += 256) hbr[i] = f2bf(xr[i] * scale * wn[i]);
    return;
  }

  // ---- weight cast+transpose ----
  int j = 0;
#pragma unroll
  for (int t = 0; t < 8; t++)
    if (bid >= J.pref[t + 1]) j = t + 1;
  int lid = bid - J.pref[j];
  int nx = J.nx[j];
  int ty = lid / nx, tx = lid - ty * nx;
  int n0 = tx * 64, k0 = ty * 64;
  int K = J.K[j];
  const float* W = J.src[j];
  short* Wt = J.dst[j];
  int Nfull = nx * 64;

  __shared__ short T[64][68];
#pragma unroll
  for (int it = 0; it < 16; it++) {
    int idx = it * 256 + tid;
    int r = idx >> 6, c = idx & 63;
    T[c][r] = f2bf(W[(size_t)(k0 + r) * Nfull + n0 + c]);
  }
  __syncthreads();
#pragma unroll
  for (int it = 0; it < 16; it++) {
    int idx = it * 256 + tid;
    int r = idx >> 6, c = idx & 63;
    Wt[(size_t)(n0 + r) * K + k0 + c] = T[r][c];
  }
}

// ---------------------------------------------------------------------------
// BM=64 x BN=128 MFMA bf16 GEMM body (4 waves of 32x64) — modes 3/4 (qkv).
// mode 3: q-pack (PRE-SCALED by 1/sqrt(192)) + fused RoPE (cols>=2048);
// mode 4: k-pack + DIRECT vt transpose write (cols>=2048).
// Both-sides XOR swizzle on As/Bs; dbuf early-issue staging.
// ---------------------------------------------------------------------------
__device__ __forceinline__ void gemm64_body(
    const short* __restrict__ A, const short* __restrict__ Bt,
    short* __restrict__ Cb, short* __restrict__ Cb2,
    int M, int N, int K, int lda, int ldb,
    int mode, int bxx, int byy) {
  __shared__ short As[2 * 64 * 64];
  __shared__ short Bs[2 * 128 * 64];
  int tid = threadIdx.x;
  int w = tid >> 6, l = tid & 63;
  int lq = l >> 4, l16 = l & 15;
  int bm = byy * 64, bn = bxx * 128;
  int wr = w >> 1, wc = w & 1;
  int wm0 = wr * 32, wn0 = wc * 64;

  f32x4 acc[2][4];
#pragma unroll
  for (int i = 0; i < 2; i++)
#pragma unroll
    for (int j = 0; j < 4; j++) acc[i][j] = (f32x4)0.f;

  int rsub = (l >> 3);                     // row-within-8 (r0 is mult of 8)
  int csub = ((l & 7) ^ rsub) << 3;        // pre-swizzled source chunk

  auto stage = [&](int buf, int k0) {
    short* Asb = As + buf * (64 * 64);
    short* Bsb = Bs + buf * (128 * 64);
#pragma unroll
    for (int i = 0; i < 2; i++) {
      int r0 = i * 32 + w * 8;
      gld_lds16(A + (size_t)(bm + r0 + rsub) * lda + k0 + csub, Asb + r0 * 64);
    }
#pragma unroll
    for (int i = 0; i < 4; i++) {
      int r0 = i * 32 + w * 8;
      gld_lds16(Bt + (size_t)(bn + r0 + rsub) * ldb + k0 + csub, Bsb + r0 * 64);
    }
  };

  stage(0, 0);
  int cur = 0;
  for (int k0 = 0; k0 < K; k0 += 64) {
    __syncthreads();
    if (k0 + 64 < K) stage(cur ^ 1, k0 + 64);
    const short* Asb = As + cur * (64 * 64);
    const short* Bsb = Bs + cur * (128 * 64);

#pragma unroll
    for (int ks = 0; ks < 2; ks++) {
      bf16x8 af[2], bfr[4];
      int sw = ((ks * 4 + lq) ^ (l16 & 7)) << 3;
#pragma unroll
      for (int mt = 0; mt < 2; mt++)
        af[mt] = *(const bf16x8*)&Asb[(wm0 + mt * 16 + l16) * 64 + sw];
#pragma unroll
      for (int nt = 0; nt < 4; nt++)
        bfr[nt] = *(const bf16x8*)&Bsb[(wn0 + nt * 16 + l16) * 64 + sw];
#pragma unroll
      for (int mt = 0; mt < 2; mt++)
#pragma unroll
        for (int nt = 0; nt < 4; nt++)
          acc[mt][nt] = __builtin_amdgcn_mfma_f32_16x16x32_bf16(af[mt], bfr[nt], acc[mt][nt], 0, 0, 0);
    }
    cur ^= 1;
  }

#pragma unroll
  for (int mt = 0; mt < 2; mt++)
#pragma unroll
    for (int nt = 0; nt < 4; nt++) {
      int col = bn + wn0 + nt * 16 + l16;
      int row0 = bm + wm0 + mt * 16 + lq * 4;
      if (mode == 4 && col >= 2048) {
        // direct vt transpose: vt[(col-2048)*SEQ + row0..row0+3]
        int cc = col - 2048;
        short4v v4;
#pragma unroll
        for (int i = 0; i < 4; i++) v4[i] = f2bf(acc[mt][nt][i]);
        *(short4v*)&Cb2[(size_t)cc * SEQ + row0] = v4;
        continue;
      }
#pragma unroll
      for (int i = 0; i < 4; i++) {
        int row = row0 + i;
        float v = acc[mt][nt][i];
        if (mode == 3) {
          if (col < 2048) {
            Cb[((size_t)(col >> 7) * M + row) * 192 + (col & 127)] =
                f2bf(v * ATT_SCALE);
          } else {
            int cc = col - 2048;
            int hh = cc >> 6, dd = cc & 63;
            float partner = __shfl_xor(v, 1);
            float inv = __expf(-((float)(dd & ~1) / 64.0f) * 9.210340372f); // ln 10000
            float ang = (float)row * inv;
            float c = __cosf(ang), s = __sinf(ang);
            float res = ((dd & 1) == 0) ? (v * c - partner * s)
                                        : (partner * s + v * c);
            Cb[((size_t)hh * M + row) * 192 + 128 + dd] = f2bf(res * ATT_SCALE);
          }
        } else {  // mode 4, col < 2048: k-pack
          Cb[((size_t)(col >> 7) * M + row) * 192 + (col & 127)] = f2bf(v);
        }
      }
    }
}

// Fused GEMM2+GEMM3 (both consume act1): bx<24 -> qb (N=3072, K=768, mode 3);
// else -> kb/vt (N=4096, K=512, mode 4). One full-device launch (1792 blocks).
__global__ __launch_bounds__(256) void gemm_qkv(
    const short* __restrict__ act1, const short* __restrict__ WT2,
    const short* __restrict__ WT3, short* __restrict__ qb,
    short* __restrict__ kb, short* __restrict__ vt) {
  int bx = blockIdx.x;
  if (bx < 24) {
    gemm64_body(act1, WT2, qb, nullptr,
                SEQ, 3072, D_CQ, N_ACT1, D_CQ, 3, bx, blockIdx.y);
  } else {
    gemm64_body(act1 + 768, WT3, kb, vt,
                SEQ, 4096, D_CKV, N_ACT1, D_CKV, 4, bx - 24, blockIdx.y);
  }
}

// ---------------------------------------------------------------------------
// 64x64 MFMA bf16 GEMM (4 waves of 32x32) — modes 0 (f32 out + addv) and
// 1 (bf16 row-major). r8-verified: higher block count for latency-bound
// small-N shapes (final GEMM 1024 blocks = 4/CU). LDS 32KB/block.
// ---------------------------------------------------------------------------
__global__ __launch_bounds__(256, 4) void gemm_bf16_6464(
    const short* __restrict__ A, const short* __restrict__ Bt,
    float* __restrict__ Cf, short* __restrict__ Cb,
    const float* __restrict__ addv, int M, int N, int K, int lda, int ldb,
    int mode) {
  __shared__ short As[2 * 64 * 64];
  __shared__ short Bs[2 * 64 * 64];
  int tid = threadIdx.x;
  int w = tid >> 6, l = tid & 63;
  int lq = l >> 4, l16 = l & 15;
  int bm = blockIdx.y * 64, bn = blockIdx.x * 64;
  int wr = w >> 1, wc = w & 1;
  int wm0 = wr * 32, wn0 = wc * 32;

  f32x4 acc[2][2];
#pragma unroll
  for (int i = 0; i < 2; i++)
#pragma unroll
    for (int j = 0; j < 2; j++) acc[i][j] = (f32x4)0.f;

  int rsub = (l >> 3);
  int csub = ((l & 7) ^ rsub) << 3;

  auto stage = [&](int buf, int k0) {
    short* Asb = As + buf * (64 * 64);
    short* Bsb = Bs + buf * (64 * 64);
#pragma unroll
    for (int i = 0; i < 2; i++) {
      int r0 = i * 32 + w * 8;
      gld_lds16(A + (size_t)(bm + r0 + rsub) * lda + k0 + csub, Asb + r0 * 64);
      gld_lds16(Bt + (size_t)(bn + r0 + rsub) * ldb + k0 + csub, Bsb + r0 * 64);
    }
  };

  stage(0, 0);
  int cur = 0;
  for (int k0 = 0; k0 < K; k0 += 64) {
    __syncthreads();
    if (k0 + 64 < K) stage(cur ^ 1, k0 + 64);
    const short* Asb = As + cur * (64 * 64);
    const short* Bsb = Bs + cur * (64 * 64);

#pragma unroll
    for (int ks = 0; ks < 2; ks++) {
      bf16x8 af[2], bfr[2];
      int sw = ((ks * 4 + lq) ^ (l16 & 7)) << 3;
#pragma unroll
      for (int mt = 0; mt < 2; mt++)
        af[mt] = *(const bf16x8*)&Asb[(wm0 + mt * 16 + l16) * 64 + sw];
#pragma unroll
      for (int nt = 0; nt < 2; nt++)
        bfr[nt] = *(const bf16x8*)&Bsb[(wn0 + nt * 16 + l16) * 64 + sw];
#pragma unroll
      for (int mt = 0; mt < 2; mt++)
#pragma unroll
        for (int nt = 0; nt < 2; nt++)
          acc[mt][nt] = __builtin_amdgcn_mfma_f32_16x16x32_bf16(af[mt], bfr[nt], acc[mt][nt], 0, 0, 0);
    }
    cur ^= 1;
  }

#pragma unroll
  for (int mt = 0; mt < 2; mt++)
#pragma unroll
    for (int nt = 0; nt < 2; nt++) {
      int col = bn + wn0 + nt * 16 + l16;
      int row0 = bm + wm0 + mt * 16 + lq * 4;
#pragma unroll
      for (int i = 0; i < 4; i++) {
        int row = row0 + i;
        float v = acc[mt][nt][i];
        if (mode == 0) {
          size_t off = (size_t)row * N + col;
          if (addv) v += addv[off];
          Cf[off] = v;
        } else {  // mode 1
          Cb[(size_t)row * N + col] = f2bf(v);
        }
      }
    }
}

// ---------------------------------------------------------------------------
// RoPE k: read bf16 cols 1280..1343 of act1, rotate, broadcast to kb heads.
// ---------------------------------------------------------------------------
__global__ void rope_k_kernel(const short* __restrict__ act1, short* __restrict__ kb) {
  int idx = blockIdx.x * blockDim.x + threadIdx.x;
  if (idx >= SEQ * 32) return;
  int j = idx & 31;
  int s = idx >> 5;
  const short* p = act1 + (size_t)s * N_ACT1 + 1280 + 2 * j;
  float x0 = bf2f(p[0]), x1 = bf2f(p[1]);
  float inv = __expf(-((float)(2 * j) / 64.0f) * 9.210340372f);
  float ang = (float)s * inv;
  float c = __cosf(ang), sn = __sinf(ang);
  short b0 = f2bf(x0 * c - x1 * sn);
  short b1 = f2bf(x0 * sn + x1 * c);
#pragma unroll
  for (int hh = 0; hh < N_H; hh++) {
    short* k = kb + ((size_t)hh * SEQ + s) * 192 + 128 + 2 * j;
    k[0] = b0;
    k[1] = b1;
  }
}

// ---------------------------------------------------------------------------
// MFMA bf16 flash attention, 4-way split-K, NO-MAX softmax, XCD-aware grid.
// Round-10: REVERT to r8-verified split config (NSPLIT=4, LPT, 1024 blocks
// = 4 blocks/CU). r9's NSPLIT=2 halved TLP and doubled the critical path
// (59.6 vs 41.7 us) — split-K is the occupancy vehicle here, its partial
// traffic is the cheaper currency. KEPT from r9: Q pre-scaled by 1/sqrt(192)
// in gemm_qkv mode 3 -> exp needs no multiply.
// r7/r8 structure: TQ=128, 4 waves x 32 Q-rows; Ks dbuf + loop-top prefetch;
// V staged at loop top; both-sides swizzle; setprio on MFMA clusters.
// ---------------------------------------------------------------------------
#define TQ 128
#define TK 64
#define KSZ (TK * 192)

__global__ __launch_bounds__(256, 2) void attn_mfma(
    const short* __restrict__ qb, const short* __restrict__ kb,
    const short* __restrict__ vt, short* __restrict__ Opart,
    float* __restrict__ Lpart) {
  int bid = blockIdx.x;
  int h = bid & 15;
  int rest = bid >> 4;            // [0, 64)
  int qt = 15 - (rest / NSPLIT);  // heavy tiles first (LPT)
  int split = rest % NSPLIT;
  int q0 = qt * TQ;
  int nk = 2 * (qt + 1);          // 64-key tiles covering rows q0..q0+127
  int tid = threadIdx.x;
  int wave = tid >> 6, lane = tid & 63;
  int lq = lane >> 4, l16 = lane & 15;

  __shared__ short Ks[2 * KSZ];    // dbuf [64 keys][24 x 16B], chunk^=(row&7)
  __shared__ short Vs[128 * 64];   // [128 dims][8 x 16B chunks], chunk^=(dim&7)
  __shared__ short Ps[TQ * 64];    // [128 rows][8 x 16B chunks], chunk^=(row&7)

  // ---- Q fragments: wave owns rows q0 + wave*32 .. +31 (2 row-tiles) ----
  bf16x8 qf[2][6];
  {
    const short* qp = qb + ((size_t)h * SEQ + q0 + wave * 32 + l16) * 192;
#pragma unroll
    for (int mt = 0; mt < 2; mt++)
#pragma unroll
      for (int ks = 0; ks < 6; ks++)
        qf[mt][ks] = *(const bf16x8*)(qp + (size_t)mt * 16 * 192 + ks * 32 + lq * 8);
  }

  bf16x8 ones;
#pragma unroll
  for (int i = 0; i < 8; i++) ones[i] = (short)0x3F80;  // bf16 1.0

  f32x4 O[2][8];
  f32x4 Ol[2];
#pragma unroll
  for (int mt = 0; mt < 2; mt++) {
    Ol[mt] = (f32x4)0.f;
#pragma unroll
    for (int i = 0; i < 8; i++) O[mt][i] = (f32x4)0.f;
  }

  // ---- K staging plan: 1536 16B slots (64 rows x 24 chunks), 6/thread.
  int goffK[6];
#pragma unroll
  for (int i = 0; i < 6; i++) {
    int s = i * 256 + tid;
    int r = s / 24;
    int c = s - r * 24;
    goffK[i] = r * 192 + ((c ^ (r & 7)) << 3);
  }
  // ---- V staging plan: 1024 16B slots (128 dims x 8 chunks), 4/thread.
  int goffV[4];
  int vrow[4];
#pragma unroll
  for (int i = 0; i < 4; i++) {
    int s = i * 256 + tid;
    int d = s >> 3;
    int p = s & 7;
    vrow[i] = d;
    goffV[i] = (p ^ (d & 7)) << 3;
  }
  const short* kb_h = kb + (size_t)h * SEQ * 192;
  const short* vt_h = vt + (size_t)h * 128 * SEQ;

  auto stage_k = [&](int k0s, int buf) {
#pragma unroll
    for (int i = 0; i < 6; i++)
      gld_lds16(kb_h + (size_t)k0s * 192 + goffK[i],
                Ks + buf * KSZ + (size_t)(i * 256 + wave * 64) * 8);
  };
  auto stage_v = [&](int k0s) {
#pragma unroll
    for (int i = 0; i < 4; i++)
      gld_lds16(vt_h + (size_t)vrow[i] * SEQ + k0s + goffV[i],
                Vs + (size_t)(i * 256 + wave * 64) * 8);
  };

  if (split < nk) stage_k(split * TK, 0);
  int kbuf = 0;

  for (int t = split; t < nk; t += NSPLIT) {
    int k0 = t * TK;
    __syncthreads();  // drains vmcnt: Ks[kbuf](t) visible; PV(t-1) reads done

    stage_v(k0);      // covered by QK^T+exp below
    if (t + NSPLIT < nk) stage_k((t + NSPLIT) * TK, kbuf ^ 1);  // dbuf prefetch

    // ---- S = Q K^T (swizzled Ks reads; B-frag shared across row-tiles) ----
    const short* Ksb = Ks + kbuf * KSZ;
    f32x4 S[2][4];
#pragma unroll
    for (int mt = 0; mt < 2; mt++)
#pragma unroll
      for (int nt = 0; nt < 4; nt++) S[mt][nt] = (f32x4)0.f;
    __builtin_amdgcn_s_setprio(1);
#pragma unroll
    for (int ks = 0; ks < 6; ks++) {
#pragma unroll
      for (int nt = 0; nt < 4; nt++) {
        int row = nt * 16 + l16;
        bf16x8 b = *(const bf16x8*)&Ksb[row * 192 +
                                        (((ks * 4 + lq) ^ (l16 & 7)) << 3)];
#pragma unroll
        for (int mt = 0; mt < 2; mt++)
          S[mt][nt] = __builtin_amdgcn_mfma_f32_16x16x32_bf16(qf[mt][ks], b, S[mt][nt], 0, 0, 0);
      }
    }
    __builtin_amdgcn_s_setprio(0);

    // ---- P = exp(S), masked -> 0 (Q pre-scaled); swizzled Ps writes ----
#pragma unroll
    for (int mt = 0; mt < 2; mt++)
#pragma unroll
      for (int i = 0; i < 4; i++) {
        int pr = wave * 32 + mt * 16 + lq * 4 + i;
        int row = q0 + pr;
        bool may = (k0 + 63 > row);
#pragma unroll
        for (int nt = 0; nt < 4; nt++) {
          float p;
          if (may && (k0 + nt * 16 + l16 > row)) p = 0.f;
          else p = __expf(S[mt][nt][i]);
          int j = nt * 16 + l16;
          Ps[pr * 64 + ((((j >> 3) ^ (pr & 7)) << 3) | (j & 7))] = f2bf(p);
        }
      }

    __syncthreads();  // drains vmcnt: Vs(t) + Ks prefetch visible

    // ---- O += P V ; Ol += P @ ones (Vs B-frag shared across row-tiles) ----
    __builtin_amdgcn_s_setprio(1);
#pragma unroll
    for (int kh = 0; kh < 2; kh++) {
      bf16x8 a[2];
#pragma unroll
      for (int mt = 0; mt < 2; mt++) {
        int prw = wave * 32 + mt * 16 + l16;
        a[mt] = *(const bf16x8*)&Ps[prw * 64 +
                                    (((kh * 4 + lq) ^ (l16 & 7)) << 3)];
        Ol[mt] = __builtin_amdgcn_mfma_f32_16x16x32_bf16(a[mt], ones, Ol[mt], 0, 0, 0);
      }
#pragma unroll
      for (int nt = 0; nt < 8; nt++) {
        int d = nt * 16 + l16;
        bf16x8 b = *(const bf16x8*)&Vs[d * 64 +
                                       (((kh * 4 + lq) ^ (d & 7)) << 3)];
#pragma unroll
        for (int mt = 0; mt < 2; mt++)
          O[mt][nt] = __builtin_amdgcn_mfma_f32_16x16x32_bf16(a[mt], b, O[mt][nt], 0, 0, 0);
      }
    }
    __builtin_amdgcn_s_setprio(0);
    kbuf ^= 1;
  }

  // ---- partial epilogue (always written, even for empty splits) ----
#pragma unroll
  for (int mt = 0; mt < 2; mt++)
#pragma unroll
    for (int i = 0; i < 4; i++) {
      int row = q0 + wave * 32 + mt * 16 + lq * 4 + i;
      size_t base = ((size_t)(split * N_H + h) * SEQ + row);
      size_t obase = base * 128;
#pragma unroll
      for (int nt = 0; nt < 8; nt++)
        Opart[obase + nt * 16 + l16] = f2bf(O[mt][nt][i]);
      if (l16 == 0) Lpart[base] = Ol[mt][i];
    }
}

// ---------------------------------------------------------------------------
// merge the NSPLIT split-K partials -> ao bf16 (s, h*128+d).
// ---------------------------------------------------------------------------
__global__ __launch_bounds__(256) void attn_merge(
    const short* __restrict__ Opart, const float* __restrict__ Lpart,
    short* __restrict__ aob) {
  int q0 = blockIdx.x * 16;
  int h = blockIdx.y;
  int tid = threadIdx.x;
#pragma unroll
  for (int i = 0; i < 8; i++) {
    int c = i * 256 + tid;
    int row = q0 + (c >> 7), d = c & 127;
    float denom = 0.f, num = 0.f;
#pragma unroll
    for (int p = 0; p < NSPLIT; p++) {
      size_t base = (size_t)(p * N_H + h) * SEQ + row;
      denom += Lpart[base];
      num += bf2f(Opart[base * 128 + d]);
    }
    aob[(size_t)row * D_MODEL + h * 128 + d] = f2bf(num / denom);
  }
}

// ---------------------------------------------------------------------------
extern "C" void kernel_launch(void* const* d_in, const int* in_sizes, int n_in,
                              void* d_out, int out_size, void* d_ws, size_t ws_size,
                              hipStream_t stream) {
  const float* x      = (const float*)d_in[0];
  // d_in[1] = mask: causal triu, handled structurally — not read.
  const float* w_norm = (const float*)d_in[2];
  const float* w_cq   = (const float*)d_in[3];
  const float* w_q    = (const float*)d_in[4];
  const float* w_qr   = (const float*)d_in[5];
  const float* w_ckv  = (const float*)d_in[6];
  const float* w_k    = (const float*)d_in[7];
  const float* w_kr   = (const float*)d_in[8];
  const float* w_v    = (const float*)d_in[9];
  const float* w_o    = (const float*)d_in[10];
  float* out = (float*)d_out;

  char* ws = (char*)d_ws;
  short* h_bf  = (short*)ws;  ws += (size_t)SEQ * D_MODEL * 2;
  short* act1  = (short*)ws;  ws += (size_t)SEQ * N_ACT1 * 2;   // [s][1408]: cq|ckv|kr|junk
  short* qb    = (short*)ws;  ws += (size_t)N_H * SEQ * 192 * 2;
  short* kb    = (short*)ws;  ws += (size_t)N_H * SEQ * 192 * 2;
  short* vt    = (short*)ws;  ws += (size_t)SEQ * D_MODEL * 2;
  short* ao_bf = (short*)ws;  ws += (size_t)SEQ * D_MODEL * 2;
  short* Opart = (short*)ws;  ws += (size_t)NSPLIT * N_H * SEQ * 128 * 2;
  float* Lpart = (float*)ws;  ws += (size_t)NSPLIT * N_H * SEQ * 4;
  short* WT1   = (short*)ws;  ws += (size_t)N_ACT1 * D_MODEL * 2;   // [1408][2048]
  short* WT2   = (short*)ws;  ws += (size_t)3072 * D_CQ * 2;        // [3072][768]
  short* WT3   = (short*)ws;  ws += (size_t)4096 * D_CKV * 2;       // [4096][512]
  short* WTO   = (short*)ws;  ws += (size_t)D_MODEL * D_MODEL * 2;  // [2048][2048]

  // ---- fused weight casts + rmsnorm (1 launch) ----
  CastJobs J;
  J.src[0] = w_cq;  J.dst[0] = WT1;                              J.K[0] = D_MODEL; J.nx[0] = D_CQ / 64;
  J.src[1] = w_ckv; J.dst[1] = WT1 + (size_t)768 * D_MODEL;      J.K[1] = D_MODEL; J.nx[1] = D_CKV / 64;
  J.src[2] = w_kr;  J.dst[2] = WT1 + (size_t)1280 * D_MODEL;     J.K[2] = D_MODEL; J.nx[2] = D_HR / 64;
  J.src[3] = w_q;   J.dst[3] = WT2;                              J.K[3] = D_CQ;    J.nx[3] = 2048 / 64;
  J.src[4] = w_qr;  J.dst[4] = WT2 + (size_t)2048 * D_CQ;        J.K[4] = D_CQ;    J.nx[4] = 1024 / 64;
  J.src[5] = w_k;   J.dst[5] = WT3;                              J.K[5] = D_CKV;   J.nx[5] = 2048 / 64;
  J.src[6] = w_v;   J.dst[6] = WT3 + (size_t)2048 * D_CKV;       J.K[6] = D_CKV;   J.nx[6] = 2048 / 64;
  J.src[7] = w_o;   J.dst[7] = WTO;                              J.K[7] = D_MODEL; J.nx[7] = 2048 / 64;
  int pref = 0;
  for (int j = 0; j < 8; j++) {
    J.pref[j] = pref;
    pref += J.nx[j] * (J.K[j] / 64);
  }
  J.pref[8] = pref;
  prep_all<<<pref + SEQ, 256, 0, stream>>>(J, x, w_norm, h_bf);

  // GEMM1: act1 = h @ [w_cq | w_ckv | w_kr | junk]  (64x64 tile: 704 blocks)
  gemm_bf16_6464<<<dim3(N_ACT1 / 64, SEQ / 64), 256, 0, stream>>>(
      h_bf, WT1, nullptr, act1, nullptr, SEQ, N_ACT1, D_MODEL,
      D_MODEL, D_MODEL, 1);

  rope_k_kernel<<<(SEQ * 32 + 255) / 256, 256, 0, stream>>>(act1, kb);

  // GEMM2+3 fused: qb (rope, pre-scaled) | kb | vt (direct transpose)
  gemm_qkv<<<dim3(24 + 32, SEQ / 64), 256, 0, stream>>>(
      act1, WT2, WT3, qb, kb, vt);

  attn_mfma<<<dim3((SEQ / TQ) * NSPLIT * N_H), 256, 0, stream>>>(qb, kb, vt, Opart, Lpart);
  attn_merge<<<dim3(SEQ / 16, N_H), 256, 0, stream>>>(Opart, Lpart, ao_bf);

  // out = ao @ w_o + x   (64x64 tile: 1024 blocks = 4/CU)
  gemm_bf16_6464<<<dim3(D_MODEL / 64, SEQ / 64), 256, 0, stream>>>(
      ao_bf, WTO, out, nullptr, x, SEQ, D_MODEL, D_MODEL,
      D_MODEL, D_MODEL, 0);
}